// Round 1
// baseline (99.949 us; speedup 1.0000x reference)
//
#include <hip/hip_runtime.h>

#define BB 16
#define CC 7
#define NN 32768
#define NCH (9*CC + 2*CC*CC)   // 161 output channels

__global__ __launch_bounds__(256) void feat_kernel(const float* __restrict__ x,
                                                   float* __restrict__ out) {
    const int n = blockIdx.x * blockDim.x + threadIdx.x;
    const int b = blockIdx.y;
    if (n >= NN) return;

    const int nm1 = (n > 0) ? n - 1 : 0;
    const int nm2 = (n > 1) ? n - 2 : 0;
    const int np1 = (n < NN - 1) ? n + 1 : n;

    const float* xb = x + (size_t)b * (2 * CC) * NN * 2;
    float* ob = out + (size_t)b * NCH * NN + n;

    float2 x1n[CC], x1p[CC], x2n[CC], x2p[CC];

#pragma unroll
    for (int c = 0; c < CC; ++c) {
        const float* p1 = xb + (size_t)c * NN * 2;
        const float* p2 = xb + (size_t)(c + CC) * NN * 2;
        float2 a_n  = *(const float2*)(p1 + 2 * n);
        float2 a_m1 = *(const float2*)(p1 + 2 * nm1);
        float2 a_m2 = *(const float2*)(p1 + 2 * nm2);
        float2 a_p1 = *(const float2*)(p1 + 2 * np1);
        float2 b_n  = *(const float2*)(p2 + 2 * n);
        float2 b_m1 = *(const float2*)(p2 + 2 * nm1);
        float2 b_m2 = *(const float2*)(p2 + 2 * nm2);
        float2 b_p1 = *(const float2*)(p2 + 2 * np1);

        // dx[n] (clamped loads give dx[0]=0 automatically), dx[n-1]
        float dx1x  = a_n.x  - a_m1.x, dx1y  = a_n.y  - a_m1.y;
        float dx1px = a_m1.x - a_m2.x, dx1py = a_m1.y - a_m2.y;
        float dx2x  = b_n.x  - b_m1.x, dx2y  = b_n.y  - b_m1.y;
        float dx2px = b_m1.x - b_m2.x, dx2py = b_m1.y - b_m2.y;

        float n1  = sqrtf(dx1x * dx1x + dx1y * dx1y);
        float n1m = sqrtf(dx1px * dx1px + dx1py * dx1py);
        float n2  = sqrtf(dx2x * dx2x + dx2y * dx2y);
        float n2m = sqrtf(dx2px * dx2px + dx2py * dx2py);

        // adx (n==0 case evaluates to 0/(0+1e-4)=0 naturally)
        float adx1 = (dx1x * dx1px + dx1y * dx1py) / (n1 * n1m + 1e-4f);
        float adx2 = (dx2x * dx2px + dx2y * dx2py) / (n2 * n2m + 1e-4f);

        // ddx[n] = dx[n] - dx[n-1]  (ddx[0]=0 automatically)
        float ddx1x = dx1x - dx1px, ddx1y = dx1y - dx1py;
        float ddx2x = dx2x - dx2px, ddx2y = dx2y - dx2py;
        float cross1 = dx1x * ddx1y - dx1y * ddx1x;
        float cross2 = dx2x * ddx2y - dx2y * ddx2x;

        float dirs = (dx1x * dx2x + dx1y * dx2y) / (n1 * n2 + 1e-6f);

        float relx = a_n.x - b_n.x, rely = a_n.y - b_n.y;
        float nrel = sqrtf(relx * relx + rely * rely);
        float lead1 =  (dx1x * relx + dx1y * rely) / (n1 * nrel + 1e-6f);
        float lead2 = -(dx2x * relx + dx2y * rely) / (n2 * nrel + 1e-6f);

        ob[(size_t)(0 * CC + c) * NN] = n1;
        ob[(size_t)(1 * CC + c) * NN] = n2;
        ob[(size_t)(2 * CC + c) * NN] = cross1;
        ob[(size_t)(3 * CC + c) * NN] = cross2;
        ob[(size_t)(4 * CC + c) * NN] = adx1;
        ob[(size_t)(5 * CC + c) * NN] = adx2;
        ob[(size_t)(6 * CC + c) * NN] = dirs;
        ob[(size_t)(7 * CC + 2 * CC * CC + c) * NN] = lead1;
        ob[(size_t)(7 * CC + 2 * CC * CC + CC + c) * NN] = lead2;

        x1n[c] = a_n; x1p[c] = a_p1;
        x2n[c] = b_n; x2p[c] = b_p1;
    }

    const bool last = (n == NN - 1);
#pragma unroll
    for (int i = 0; i < CC; ++i) {
#pragma unroll
        for (int j = 0; j < CC; ++j) {
            const int c1 = ((j - i - 1) % CC + CC) % CC;  // compile-time (full unroll)
            float dx = x1n[c1].x - x2n[j].x + 1e-6f;
            float dy = x1n[c1].y - x2n[j].y + 1e-6f;
            float dcur = sqrtf(dx * dx + dy * dy);
            float ex = x1p[c1].x - x2p[j].x + 1e-6f;
            float ey = x1p[c1].y - x2p[j].y + 1e-6f;
            float dnext = sqrtf(ex * ex + ey * ey);
            float dd = last ? -dcur : (dnext - dcur);
            ob[(size_t)(7 * CC + i * CC + j) * NN] = dcur;
            ob[(size_t)(7 * CC + CC * CC + i * CC + j) * NN] = dd;
        }
    }
}

extern "C" void kernel_launch(void* const* d_in, const int* in_sizes, int n_in,
                              void* d_out, int out_size, void* d_ws, size_t ws_size,
                              hipStream_t stream) {
    const float* x = (const float*)d_in[0];
    float* out = (float*)d_out;
    dim3 grid(NN / 256, BB);
    feat_kernel<<<grid, 256, 0, stream>>>(x, out);
}